// Round 1
// baseline (836.150 us; speedup 1.0000x reference)
//
#include <hip/hip_runtime.h>
#include <math.h>

#define N64    64
#define LSEQ   8192
#define CHUNK  64
#define NCHUNK 128
#define NBATCH 2048

typedef float Row68[68];

// O = Aop @ Bop (+ I if addI) (+ Badd elementwise if non-null). 256 threads.
__device__ __forceinline__ void mm64(Row68* O, Row68* Aop, Row68* Bop,
                                     Row68* Badd, int addI, int t) {
  const int r  = t >> 2;
  const int c0 = (t & 3) << 4;
  float acc[16];
#pragma unroll
  for (int k = 0; k < 16; ++k) acc[k] = 0.f;
  for (int m = 0; m < N64; ++m) {
    float a = Aop[r][m];
#pragma unroll
    for (int k = 0; k < 16; ++k) acc[k] += a * Bop[m][c0 + k];
  }
#pragma unroll
  for (int k = 0; k < 16; ++k) {
    float v = acc[k];
    if (addI && r == (c0 + k)) v += 1.f;
    if (Badd) v += Badd[r][c0 + k];
    O[r][c0 + k] = v;
  }
}

// Precompute, single workgroup of 256 threads.
// ws layout (floats): [0]P(64x64)=Ab^64  [4096]A1(64x64): row i = C*Ab^(i+1)
//                     [8192]Brev(64x64): Brev[n][j] = (Ab^(63-j) Bb)[n]
//                     [12288]K(64)       [12352]Bcols tmp (64x64): row r = Ab^r Bb
__global__ void __launch_bounds__(256)
ssm_pre(const float* __restrict__ Ag, const float* __restrict__ Bg,
        const float* __restrict__ Cg, const float* __restrict__ lsg,
        float* __restrict__ ws) {
  __shared__ float b0[64][68], b1[64][68], b2[64][68];
  __shared__ float Bb0[64];
  const int t = threadIdx.x;
  const float step = expf(lsg[0]);
  const float h = 0.5f * step;

  // b0 = h*A ; b1 = I + h*A
  for (int i = t; i < 4096; i += 256) {
    int r = i >> 6, c = i & 63;
    float v = h * Ag[i];
    b0[r][c] = v;
    b1[r][c] = v + ((r == c) ? 1.f : 0.f);
  }
  __syncthreads();

  // Neumann/Horner: BL = (I - hA)^-1 ~= I + hA(I + hA(...)), 10 iters -> order 11
  Row68* cur = b1;
  Row68* oth = b2;
  for (int it = 0; it < 10; ++it) {
    mm64(oth, b0, cur, nullptr, 1, t);
    __syncthreads();
    Row68* tmp = cur; cur = oth; oth = tmp;
  }
  // Bb = step * BL @ B
  if (t < 64) {
    float acc = 0.f;
    for (int m = 0; m < 64; ++m) acc += cur[t][m] * Bg[m];
    Bb0[t] = step * acc;
  }
  __syncthreads();
  // Ab = BL + hA @ BL   (commuting series in hA)
  mm64(oth, b0, cur, cur, 0, t);
  __syncthreads();

  Row68* pw = oth;   // current power of Ab (starts at Ab^1)
  Row68* f0 = b0;    // free
  Row68* f1 = cur;   // free

  float* wsP  = ws;
  float* wsA1 = ws + 4096;
  float* wsBr = ws + 8192;
  float* wsK  = ws + 12288;
  float* gB   = ws + 12352;

  // Arows[0] = C @ Ab ; Bcols[0] = Bb
  if (t < 64) {
    float acc = 0.f;
    for (int m = 0; m < 64; ++m) acc += Cg[m] * pw[m][t];
    wsA1[t] = acc;
    gB[t] = Bb0[t];
  }
  __syncthreads();

  // Block-doubling: rows/cols 1..63 + squarings up to Ab^32
  int which = 0;
  for (int k = 1; k <= 32; k <<= 1) {
    // Bcols[k+j][n] = sum_m (Ab^k)[n][m] * Bcols[j][m]
    for (int i = t; i < k * 64; i += 256) {
      int j = i >> 6, n = i & 63;
      float acc = 0.f;
      for (int m = 0; m < 64; ++m) acc += pw[n][m] * gB[j * 64 + m];
      gB[(k + j) * 64 + n] = acc;
    }
    // Arows[k+j][n] = sum_m Arows[j][m] * (Ab^k)[m][n]
    for (int i = t; i < k * 64; i += 256) {
      int j = i >> 6, n = i & 63;
      float acc = 0.f;
      for (int m = 0; m < 64; ++m) acc += wsA1[j * 64 + m] * pw[m][n];
      wsA1[(k + j) * 64 + n] = acc;
    }
    __syncthreads();
    if (k < 32) {
      Row68* tgt = which ? f1 : f0;
      mm64(tgt, pw, pw, nullptr, 0, t);
      __syncthreads();
      if (which) f1 = pw; else f0 = pw;
      pw = tgt;
      which ^= 1;
    }
  }

  // P = Ab^64 = pw @ pw -> global
  {
    int r = t >> 2, c0 = (t & 3) << 4;
    float acc[16];
#pragma unroll
    for (int k = 0; k < 16; ++k) acc[k] = 0.f;
    for (int m = 0; m < 64; ++m) {
      float a = pw[r][m];
#pragma unroll
      for (int k = 0; k < 16; ++k) acc[k] += a * pw[m][c0 + k];
    }
#pragma unroll
    for (int k = 0; k < 16; ++k) wsP[r * 64 + c0 + k] = acc[k];
  }
  __syncthreads();
  // K[r] = C . Bcols[r]
  if (t < 64) {
    float acc = 0.f;
    for (int m = 0; m < 64; ++m) acc += Cg[m] * gB[t * 64 + m];
    wsK[t] = acc;
  }
  // Brev[n][j] = Bcols[63-j][n]
  for (int i = t; i < 4096; i += 256) {
    int n = i >> 6, j = i & 63;
    wsBr[i] = gB[(63 - j) * 64 + n];
  }
}

// Main fused chunked-SSM kernel.
// block = 256 threads = 4 waves; wave <-> one batch row; lane <-> time/state index.
__global__ void __launch_bounds__(256, 2)
ssm_main(const float* __restrict__ u, const float* __restrict__ Dg,
         const float* __restrict__ ws, float* __restrict__ y) {
  const int lane = threadIdx.x & 63;
  const int bl   = threadIdx.x >> 6;
  const int brow = blockIdx.x * 4 + bl;

  const float* wsP  = ws;
  const float* wsA1 = ws + 4096;
  const float* wsBr = ws + 8192;
  const float* wsK  = ws + 12288;

  __shared__ float u_lz[4][144];  // [wave][64 zeros | 64 chunk | 16 pad]
  __shared__ float sK[64];

  // Per-lane matrix rows in VGPRs (row = this lane's state/time index).
  float pr[64], ar[64], br[64];
#pragma unroll
  for (int q = 0; q < 16; ++q) {
    float4 v0 = *(const float4*)(wsP  + lane * 64 + 4 * q);
    pr[4*q] = v0.x; pr[4*q+1] = v0.y; pr[4*q+2] = v0.z; pr[4*q+3] = v0.w;
    float4 v1 = *(const float4*)(wsA1 + lane * 64 + 4 * q);
    ar[4*q] = v1.x; ar[4*q+1] = v1.y; ar[4*q+2] = v1.z; ar[4*q+3] = v1.w;
    float4 v2 = *(const float4*)(wsBr + lane * 64 + 4 * q);
    br[4*q] = v2.x; br[4*q+1] = v2.y; br[4*q+2] = v2.z; br[4*q+3] = v2.w;
  }
  if (threadIdx.x < 64) sK[threadIdx.x] = wsK[threadIdx.x];
  u_lz[bl][lane] = 0.f;  // left zero pad for causal intra-chunk conv

  const float D0 = Dg[0];
  const float* urow = u + (size_t)brow * LSEQ;
  float*       yrow = y + (size_t)brow * LSEQ;

  float s = 0.f;  // lane n holds state component s[n] for this wave's batch row

  for (int c = 0; c < NCHUNK; ++c) {
    float uval = urow[c * CHUNK + lane];
    __syncthreads();                 // prior chunk's LDS reads done
    u_lz[bl][64 + lane] = uval;
    __syncthreads();                 // chunk staged

    float y_acc = D0 * uval;
    float s_acc = 0.f;

    // State part: y += A1[i][:].s ; s_new += P[n][:].s  (s broadcast via readlane)
#pragma unroll
    for (int m = 0; m < 64; ++m) {
      float s_m = __shfl(s, m, 64);
      y_acc += ar[m] * s_m;
      s_acc += pr[m] * s_m;
    }
    // Input part of state update: s_new += sum_j Brev[n][j] * u[cT+j]
#pragma unroll
    for (int q = 0; q < 16; ++q) {
      float4 uq = *(const float4*)&u_lz[bl][64 + 4 * q];
      s_acc += br[4*q]   * uq.x + br[4*q+1] * uq.y
             + br[4*q+2] * uq.z + br[4*q+3] * uq.w;
    }
    // Intra-chunk causal conv: y += sum_j K[j] * u[cT + i - j] (zeros for j > i)
#pragma unroll
    for (int j = 0; j < 64; ++j) {
      y_acc += sK[j] * u_lz[bl][64 + lane - j];
    }

    s = s_acc;
    yrow[c * CHUNK + lane] = y_acc;
  }
}

extern "C" void kernel_launch(void* const* d_in, const int* in_sizes, int n_in,
                              void* d_out, int out_size, void* d_ws, size_t ws_size,
                              hipStream_t stream) {
  const float* u  = (const float*)d_in[0];
  const float* A  = (const float*)d_in[1];
  const float* B  = (const float*)d_in[2];
  const float* C  = (const float*)d_in[3];
  const float* D  = (const float*)d_in[4];
  const float* ls = (const float*)d_in[5];
  float* ws  = (float*)d_ws;
  float* out = (float*)d_out;

  ssm_pre<<<dim3(1), dim3(256), 0, stream>>>(A, B, C, ls, ws);
  ssm_main<<<dim3(NBATCH / 4), dim3(256), 0, stream>>>(u, D, ws, out);
}

// Round 2
// 520.582 us; speedup vs baseline: 1.6062x; 1.6062x over previous
//
#include <hip/hip_runtime.h>
#include <math.h>

#define N64    64
#define LSEQ   8192
#define CHUNK  64
#define NCHUNK 128
#define NBATCH 2048
#define CG     8     // chunks per conv wave

// ws float layout:
//   [0]     P    (64x64)  = Ab^64
//   [4096]  A1   (64x64)  row i = C*Ab^(i+1)
//   [8192]  Brev (64x64)  Brev[n][j] = (Ab^(63-j) Bb)[n]
//   [12288] K    (64)
//   [12416] Kmat (64x64)  Kmat[i][j] = (i>=j) ? K[i-j] : 0
//   [16512] gB tmp (64x64)
//   [20608] v    (NBATCH*NCHUNK*64)   -- only if ws_size permits
#define WS_P   0
#define WS_A1  4096
#define WS_BR  8192
#define WS_K   12288
#define WS_KM  12416
#define WS_GB  16512
#define WS_V   20608

typedef float Row68[68];

__device__ __forceinline__ float rl(float v, int l) {
  return __builtin_bit_cast(float,
      __builtin_amdgcn_readlane(__builtin_bit_cast(int, v), l));
}

// O = Aop @ Bop (+ I if addI) (+ Badd elementwise if non-null). 256 threads.
__device__ __forceinline__ void mm64(Row68* O, Row68* Aop, Row68* Bop,
                                     Row68* Badd, int addI, int t) {
  const int r  = t >> 2;
  const int c0 = (t & 3) << 4;
  float acc[16];
#pragma unroll
  for (int k = 0; k < 16; ++k) acc[k] = 0.f;
  for (int m = 0; m < N64; ++m) {
    float a = Aop[r][m];
#pragma unroll
    for (int k = 0; k < 16; ++k) acc[k] += a * Bop[m][c0 + k];
  }
#pragma unroll
  for (int k = 0; k < 16; ++k) {
    float v = acc[k];
    if (addI && r == (c0 + k)) v += 1.f;
    if (Badd) v += Badd[r][c0 + k];
    O[r][c0 + k] = v;
  }
}

// Precompute, single workgroup of 256 threads.
__global__ void __launch_bounds__(256)
ssm_pre(const float* __restrict__ Ag, const float* __restrict__ Bg,
        const float* __restrict__ Cg, const float* __restrict__ lsg,
        float* __restrict__ ws) {
  __shared__ float b0[64][68], b1[64][68], b2[64][68];
  __shared__ float Bb0[64];
  const int t = threadIdx.x;
  const float step = expf(lsg[0]);
  const float h = 0.5f * step;

  // b0 = h*A ; b1 = I + h*A
  for (int i = t; i < 4096; i += 256) {
    int r = i >> 6, c = i & 63;
    float v = h * Ag[i];
    b0[r][c] = v;
    b1[r][c] = v + ((r == c) ? 1.f : 0.f);
  }
  __syncthreads();

  // Neumann/Horner: BL = (I - hA)^-1 ~= I + hA(I + hA(...)), order 11
  Row68* cur = b1;
  Row68* oth = b2;
  for (int it = 0; it < 10; ++it) {
    mm64(oth, b0, cur, nullptr, 1, t);
    __syncthreads();
    Row68* tmp = cur; cur = oth; oth = tmp;
  }
  // Bb = step * BL @ B
  if (t < 64) {
    float acc = 0.f;
    for (int m = 0; m < 64; ++m) acc += cur[t][m] * Bg[m];
    Bb0[t] = step * acc;
  }
  __syncthreads();
  // Ab = BL + hA @ BL
  mm64(oth, b0, cur, cur, 0, t);
  __syncthreads();

  Row68* pw = oth;
  Row68* f0 = b0;
  Row68* f1 = cur;

  float* wsP  = ws + WS_P;
  float* wsA1 = ws + WS_A1;
  float* wsBr = ws + WS_BR;
  float* wsK  = ws + WS_K;
  float* wsKm = ws + WS_KM;
  float* gB   = ws + WS_GB;

  if (t < 64) {
    float acc = 0.f;
    for (int m = 0; m < 64; ++m) acc += Cg[m] * pw[m][t];
    wsA1[t] = acc;
    gB[t] = Bb0[t];
  }
  __syncthreads();

  // Block-doubling for Arows / Bcols + squarings up to Ab^32
  int which = 0;
  for (int k = 1; k <= 32; k <<= 1) {
    for (int i = t; i < k * 64; i += 256) {
      int j = i >> 6, n = i & 63;
      float acc = 0.f;
      for (int m = 0; m < 64; ++m) acc += pw[n][m] * gB[j * 64 + m];
      gB[(k + j) * 64 + n] = acc;
    }
    for (int i = t; i < k * 64; i += 256) {
      int j = i >> 6, n = i & 63;
      float acc = 0.f;
      for (int m = 0; m < 64; ++m) acc += wsA1[j * 64 + m] * pw[m][n];
      wsA1[(k + j) * 64 + n] = acc;
    }
    __syncthreads();
    if (k < 32) {
      Row68* tgt = which ? f1 : f0;
      mm64(tgt, pw, pw, nullptr, 0, t);
      __syncthreads();
      if (which) f1 = pw; else f0 = pw;
      pw = tgt;
      which ^= 1;
    }
  }

  // P = Ab^64 -> global
  {
    int r = t >> 2, c0 = (t & 3) << 4;
    float acc[16];
#pragma unroll
    for (int k = 0; k < 16; ++k) acc[k] = 0.f;
    for (int m = 0; m < 64; ++m) {
      float a = pw[r][m];
#pragma unroll
      for (int k = 0; k < 16; ++k) acc[k] += a * pw[m][c0 + k];
    }
#pragma unroll
    for (int k = 0; k < 16; ++k) wsP[r * 64 + c0 + k] = acc[k];
  }
  __syncthreads();
  // K[r] = C . Bcols[r]
  if (t < 64) {
    float acc = 0.f;
    for (int m = 0; m < 64; ++m) acc += Cg[m] * gB[t * 64 + m];
    wsK[t] = acc;
  }
  // Brev[n][j] = Bcols[63-j][n]
  for (int i = t; i < 4096; i += 256) {
    int n = i >> 6, j = i & 63;
    wsBr[i] = gB[(63 - j) * 64 + n];
  }
  __syncthreads();
  // Kmat[i][j] = (i>=j) ? K[i-j] : 0
  for (int i = t; i < 4096; i += 256) {
    int r = i >> 6, c = i & 63;
    wsKm[i] = (r >= c) ? wsK[r - c] : 0.f;
  }
}

// Phase 1: per (row, chunk-group of CG): y_zero = Kmat@u + D*u ; v = Brev@u.
// lane = time-within-chunk. No LDS, no barriers; broadcasts via v_readlane.
template <bool WRITEV>
__global__ void __launch_bounds__(256, 3)
ssm_conv(const float* __restrict__ u, const float* __restrict__ Dg,
         const float* __restrict__ ws, float* __restrict__ y,
         float* __restrict__ v) {
  const int lane = threadIdx.x & 63;
  const int wid  = (blockIdx.x << 2) + (threadIdx.x >> 6);
  const int row  = wid >> 4;      // 2048 rows
  const int g    = wid & 15;      // 16 groups of CG=8 chunks

  const float* wsKm = ws + WS_KM;
  const float* wsBr = ws + WS_BR;

  float kr[64], br[64];
#pragma unroll
  for (int q = 0; q < 16; ++q) {
    float4 a = *(const float4*)(wsKm + lane * 64 + 4 * q);
    kr[4*q] = a.x; kr[4*q+1] = a.y; kr[4*q+2] = a.z; kr[4*q+3] = a.w;
    if (WRITEV) {
      float4 b = *(const float4*)(wsBr + lane * 64 + 4 * q);
      br[4*q] = b.x; br[4*q+1] = b.y; br[4*q+2] = b.z; br[4*q+3] = b.w;
    }
  }
  const float D0 = Dg[0];
  const float* urow = u + (size_t)row * LSEQ + g * (CG * CHUNK);
  float*       yrow = y + (size_t)row * LSEQ + g * (CG * CHUNK);
  float*       vrow = WRITEV ? (v + ((size_t)row * NCHUNK + g * CG) * 64) : nullptr;

#pragma unroll
  for (int c = 0; c < CG; ++c) {
    float uval = urow[c * CHUNK + lane];
    float yacc = D0 * uval;
    float vacc = 0.f;
#pragma unroll
    for (int j = 0; j < 64; ++j) {
      float uj = rl(uval, j);
      yacc += kr[j] * uj;
      if (WRITEV) vacc += br[j] * uj;
    }
    yrow[c * CHUNK + lane] = yacc;
    if (WRITEV) vrow[c * CHUNK + lane] = vacc;
  }
}

// Phase 2: per-row scan. s <- P s + v_c ; y[c] += A1 s (s = state BEFORE chunk c).
// Variant A: v precomputed. Variant B: v computed on the fly from u (small ws).
template <bool HAVEV>
__global__ void __launch_bounds__(256, 2)
ssm_scan(const float* __restrict__ u, const float* __restrict__ ws,
         const float* __restrict__ v, float* __restrict__ y) {
  const int lane = threadIdx.x & 63;
  const int row  = (blockIdx.x << 2) + (threadIdx.x >> 6);

  const float* wsP  = ws + WS_P;
  const float* wsA1 = ws + WS_A1;
  const float* wsBr = ws + WS_BR;

  float pr[64], ar[64], br[64];
#pragma unroll
  for (int q = 0; q < 16; ++q) {
    float4 a = *(const float4*)(wsP + lane * 64 + 4 * q);
    pr[4*q] = a.x; pr[4*q+1] = a.y; pr[4*q+2] = a.z; pr[4*q+3] = a.w;
    float4 b = *(const float4*)(wsA1 + lane * 64 + 4 * q);
    ar[4*q] = b.x; ar[4*q+1] = b.y; ar[4*q+2] = b.z; ar[4*q+3] = b.w;
    if (!HAVEV) {
      float4 c = *(const float4*)(wsBr + lane * 64 + 4 * q);
      br[4*q] = c.x; br[4*q+1] = c.y; br[4*q+2] = c.z; br[4*q+3] = c.w;
    }
  }

  const float* vrow = HAVEV ? (v + (size_t)row * NCHUNK * 64) : nullptr;
  const float* urow = u + (size_t)row * LSEQ;
  float*       yrow = y + (size_t)row * LSEQ;

  float s = 0.f;
  // 1-chunk-ahead prefetch
  float pv = HAVEV ? vrow[lane] : urow[lane];
  float py = yrow[lane];

  for (int c = 0; c < NCHUNK; ++c) {
    float xcur = pv;      // v_c (A) or u_c (B)
    float ycur = py;
    if (c + 1 < NCHUNK) {
      pv = HAVEV ? vrow[(c + 1) * 64 + lane] : urow[(c + 1) * 64 + lane];
      py = yrow[(c + 1) * 64 + lane];
    }
    float yacc = ycur;
    float sacc;
    if (HAVEV) {
      sacc = xcur;
    } else {
      sacc = 0.f;
#pragma unroll
      for (int j = 0; j < 64; ++j) sacc += br[j] * rl(xcur, j);
    }
#pragma unroll
    for (int m = 0; m < 64; ++m) {
      float sm = rl(s, m);
      yacc += ar[m] * sm;
      sacc += pr[m] * sm;
    }
    yrow[c * CHUNK + lane] = yacc;
    s = sacc;
  }
}

extern "C" void kernel_launch(void* const* d_in, const int* in_sizes, int n_in,
                              void* d_out, int out_size, void* d_ws, size_t ws_size,
                              hipStream_t stream) {
  const float* u  = (const float*)d_in[0];
  const float* A  = (const float*)d_in[1];
  const float* B  = (const float*)d_in[2];
  const float* C  = (const float*)d_in[3];
  const float* D  = (const float*)d_in[4];
  const float* ls = (const float*)d_in[5];
  float* ws  = (float*)d_ws;
  float* out = (float*)d_out;

  const size_t needV = (size_t)(WS_V + (size_t)NBATCH * NCHUNK * 64) * sizeof(float);
  const bool haveV = ws_size >= needV;
  float* v = ws + WS_V;

  ssm_pre<<<dim3(1), dim3(256), 0, stream>>>(A, B, C, ls, ws);
  if (haveV) {
    ssm_conv<true><<<dim3(NBATCH * 16 / 4), dim3(256), 0, stream>>>(u, D, ws, out, v);
    ssm_scan<true><<<dim3(NBATCH / 4), dim3(256), 0, stream>>>(u, ws, v, out);
  } else {
    ssm_conv<false><<<dim3(NBATCH * 16 / 4), dim3(256), 0, stream>>>(u, D, ws, out, nullptr);
    ssm_scan<false><<<dim3(NBATCH / 4), dim3(256), 0, stream>>>(u, ws, nullptr, out);
  }
}